// Round 3
// baseline (122.882 us; speedup 1.0000x reference)
//
#include <hip/hip_runtime.h>

// CenterLoss: mean over B rows of clip(||x_b - centers[label_b]||^2, 1e-12, 1e12)
// labels are exact one-hot fp32 rows -> dense dot == row gather (bit-exact).
//
// R1: 8192 same-address atomics serialized at the TCC (110 us kernel).
// R2: per-block partial stores + 1-block reduce -> 115.9 us total. ~95 us is
//     the harness's fixed 268 MB d_ws re-poison + reset; our kernels ~20 us
//     vs a ~15.5 us mandatory-fetch floor (98 MB @ 6.3 TB/s).
// R4: wave-per-row + nontemporal loads REGRESSED (122.3 us).
// R5: revert to R2 (measured best).
// R6: fused last-block reduce via agent-scope ACQ_REL ticket REGRESSED HARD
//     (345.7 us; kernel 273 us @ 264 GB/s). Per-block agent-scope release
//     forces an L2 writeback on non-coherent per-XCD L2s -> 8192 serialized
//     L2 drains. Kernel boundary IS the cheap release on CDNA4.
// R7: 256-chunk early-exit label scan -> 114.45 us (-1.95, matched
//     prediction). Confirms controllable time is traffic-proportional.
// R8 (this): wave-granular (64-float) label scan by wave 0 with __any
//     ballot exit. Avg floats/row 501 -> 407 (floor ~390 at line
//     granularity): -3.1 MB labels traffic ~= -0.5 us. Latency check:
//     per-CU serial-chain time (32 blk x ~2.8 us / 8 resident = 11.2 us)
//     still < per-CU BW time (13.5 us) -> remains BW-bound. Also drops the
//     per-chunk double barrier (single block barrier total).

#define BATCH 8192
#define NUM_CLASSES 751
#define FEAT_DIM 2048

__global__ __launch_bounds__(256) void center_loss_kernel(
    const float* __restrict__ x,
    const float* __restrict__ labels,
    const float* __restrict__ centers,
    float* __restrict__ partials)
{
    const int row = blockIdx.x;
    const int tid = threadIdx.x;

    // ---- Prefetch x row (independent of labels) to overlap HBM latency ----
    const float4* __restrict__ xrow = (const float4*)(x + (size_t)row * FEAT_DIM);
    float4 xv0 = xrow[tid];
    float4 xv1 = xrow[tid + 256];

    // ---- One-hot index: wave 0 scans 64 floats/round, __any early exit.
    // Exactly one lane ever finds a hit, so a single LDS write + one block
    // barrier suffices (no per-chunk write/read race).
    __shared__ int s_idx;
    const float* lrow = labels + (size_t)row * NUM_CLASSES;
    if (tid < 64) {
        int found = -1;
        #pragma unroll 1
        for (int b = 0; b < 12; ++b) {          // ceil(751/64) = 12
            const int c = b * 64 + tid;
            float v = (c < NUM_CLASSES) ? lrow[c] : 0.0f;
            if (v > 0.5f) found = c;
            if (__any(found >= 0)) break;        // uniform across wave
        }
        if (found >= 0) s_idx = found;           // the single finding lane
    }
    __syncthreads();
    const int idx = s_idx;

    // ---- Gather center row and accumulate squared distance ----
    const float4* __restrict__ crow = (const float4*)(centers + (size_t)idx * FEAT_DIM);
    float4 cv0 = crow[tid];
    float4 cv1 = crow[tid + 256];

    float dx = xv0.x - cv0.x, dy = xv0.y - cv0.y, dz = xv0.z - cv0.z, dw = xv0.w - cv0.w;
    float sum = dx * dx + dy * dy + dz * dz + dw * dw;
    dx = xv1.x - cv1.x; dy = xv1.y - cv1.y; dz = xv1.z - cv1.z; dw = xv1.w - cv1.w;
    sum += dx * dx + dy * dy + dz * dz + dw * dw;

    // ---- wave-64 shuffle reduction ----
    #pragma unroll
    for (int off = 32; off > 0; off >>= 1)
        sum += __shfl_down(sum, off, 64);

    __shared__ float s_part[4];
    const int wave = tid >> 6;
    const int lane = tid & 63;
    if (lane == 0) s_part[wave] = sum;
    __syncthreads();

    if (tid == 0) {
        float ps = s_part[0] + s_part[1] + s_part[2] + s_part[3];
        ps = fminf(fmaxf(ps, 1e-12f), 1e12f);   // clip
        partials[row] = ps;                      // deterministic store, no atomic
    }
}

// Reduce 8192 partials (32 KB, L2/L3-hot) -> mean. One block, 256 threads.
__global__ __launch_bounds__(256) void reduce_kernel(
    const float* __restrict__ partials,
    float* __restrict__ out)
{
    const int tid = threadIdx.x;
    const float4* __restrict__ p4 = (const float4*)partials;  // 2048 float4s

    float sum = 0.0f;
    #pragma unroll
    for (int k = 0; k < 8; ++k) {
        float4 v = p4[tid + 256 * k];
        sum += v.x + v.y + v.z + v.w;
    }

    #pragma unroll
    for (int off = 32; off > 0; off >>= 1)
        sum += __shfl_down(sum, off, 64);

    __shared__ float s_part[4];
    const int wave = tid >> 6;
    const int lane = tid & 63;
    if (lane == 0) s_part[wave] = sum;
    __syncthreads();

    if (tid == 0) {
        float total = s_part[0] + s_part[1] + s_part[2] + s_part[3];
        out[0] = total * (1.0f / (float)BATCH);
    }
}

extern "C" void kernel_launch(void* const* d_in, const int* in_sizes, int n_in,
                              void* d_out, int out_size, void* d_ws, size_t ws_size,
                              hipStream_t stream)
{
    const float* x       = (const float*)d_in[0];
    const float* labels  = (const float*)d_in[1];
    const float* centers = (const float*)d_in[2];
    float* out      = (float*)d_out;
    float* partials = (float*)d_ws;   // 8192 floats, every slot overwritten

    center_loss_kernel<<<BATCH, 256, 0, stream>>>(x, labels, centers, partials);
    reduce_kernel<<<1, 256, 0, stream>>>(partials, out);
}

// Round 4
// 114.221 us; speedup vs baseline: 1.0758x; 1.0758x over previous
//
#include <hip/hip_runtime.h>

// CenterLoss: mean over B rows of clip(||x_b - centers[label_b]||^2, 1e-12, 1e12)
// labels are exact one-hot fp32 rows -> dense dot == row gather (bit-exact).
//
// R1: 8192 same-address atomics serialized at the TCC (110 us kernel).
// R2: per-block partial stores + 1-block reduce -> 115.9 us total. ~95 us is
//     the harness's fixed 268 MB d_ws re-poison + reset.
// R4: wave-per-row + nontemporal loads REGRESSED (122.3 us).
// R5: revert to R2 (measured best).
// R6: fused last-block reduce via agent-scope ACQ_REL ticket REGRESSED HARD
//     (345.7 us). Per-block agent-scope release forces an L2 writeback on
//     non-coherent per-XCD L2s -> 8192 serialized L2 drains. Kernel boundary
//     IS the cheap release on CDNA4. Counter note: FETCH was ~70.7 MB =
//     x (67.1) + centers (6.2) only -> labels are largely L3-resident;
//     label-scan savings are L3-BW/latency wins, not HBM bytes.
// R7: 256-chunk early-exit label scan -> 114.45 us (-1.95, matched
//     prediction). Measured best.
// R8: wave-granular 64-float scan REGRESSED (122.9 us): 12 dependent
//     HBM/L3 round-trips on the critical path, one wave active. Dependent-
//     chain latency is per-block, not amortized by TLP. Wide parallel scan
//     with ~2 rounds beats narrow low-traffic scan with ~6-12 rounds.
// R9 (this): revert verbatim to R7 (measured best, at the roofline:
//     controllable ~19.5 us vs ~11.6 us HBM floor + L3 label reads +
//     ~2.5 us fixed reduce launch; every remaining lever tested and
//     rejected).

#define BATCH 8192
#define NUM_CLASSES 751
#define FEAT_DIM 2048

__global__ __launch_bounds__(256) void center_loss_kernel(
    const float* __restrict__ x,
    const float* __restrict__ labels,
    const float* __restrict__ centers,
    float* __restrict__ partials)
{
    const int row = blockIdx.x;
    const int tid = threadIdx.x;

    // ---- Prefetch x row (independent of labels) to overlap HBM latency ----
    const float4* __restrict__ xrow = (const float4*)(x + (size_t)row * FEAT_DIM);
    float4 xv0 = xrow[tid];
    float4 xv1 = xrow[tid + 256];

    // ---- Find the one-hot index: chunked scan with block-wide early exit.
    // Avg chunks read = 1.98 of 3; all 4 waves issue in parallel, only ~2
    // dependent rounds on the critical path.
    __shared__ int s_idx;
    if (tid == 0) s_idx = -1;
    __syncthreads();

    const float* lrow = labels + (size_t)row * NUM_CLASSES;
    int idx = -1;
    #pragma unroll
    for (int k = 0; k < 3; ++k) {
        const int c = k * 256 + tid;
        if (c < NUM_CLASSES && lrow[c] > 0.5f) s_idx = c;  // one thread writes
        __syncthreads();
        idx = s_idx;
        __syncthreads();          // protect reads from next-chunk writes
        if (idx >= 0) break;      // uniform: s_idx identical across block
    }

    // ---- Gather center row and accumulate squared distance ----
    const float4* __restrict__ crow = (const float4*)(centers + (size_t)idx * FEAT_DIM);
    float4 cv0 = crow[tid];
    float4 cv1 = crow[tid + 256];

    float dx = xv0.x - cv0.x, dy = xv0.y - cv0.y, dz = xv0.z - cv0.z, dw = xv0.w - cv0.w;
    float sum = dx * dx + dy * dy + dz * dz + dw * dw;
    dx = xv1.x - cv1.x; dy = xv1.y - cv1.y; dz = xv1.z - cv1.z; dw = xv1.w - cv1.w;
    sum += dx * dx + dy * dy + dz * dz + dw * dw;

    // ---- wave-64 shuffle reduction ----
    #pragma unroll
    for (int off = 32; off > 0; off >>= 1)
        sum += __shfl_down(sum, off, 64);

    __shared__ float s_part[4];
    const int wave = tid >> 6;
    const int lane = tid & 63;
    if (lane == 0) s_part[wave] = sum;
    __syncthreads();

    if (tid == 0) {
        float ps = s_part[0] + s_part[1] + s_part[2] + s_part[3];
        ps = fminf(fmaxf(ps, 1e-12f), 1e12f);   // clip
        partials[row] = ps;                      // deterministic store, no atomic
    }
}

// Reduce 8192 partials (32 KB, L2/L3-hot) -> mean. One block, 256 threads.
__global__ __launch_bounds__(256) void reduce_kernel(
    const float* __restrict__ partials,
    float* __restrict__ out)
{
    const int tid = threadIdx.x;
    const float4* __restrict__ p4 = (const float4*)partials;  // 2048 float4s

    float sum = 0.0f;
    #pragma unroll
    for (int k = 0; k < 8; ++k) {
        float4 v = p4[tid + 256 * k];
        sum += v.x + v.y + v.z + v.w;
    }

    #pragma unroll
    for (int off = 32; off > 0; off >>= 1)
        sum += __shfl_down(sum, off, 64);

    __shared__ float s_part[4];
    const int wave = tid >> 6;
    const int lane = tid & 63;
    if (lane == 0) s_part[wave] = sum;
    __syncthreads();

    if (tid == 0) {
        float total = s_part[0] + s_part[1] + s_part[2] + s_part[3];
        out[0] = total * (1.0f / (float)BATCH);
    }
}

extern "C" void kernel_launch(void* const* d_in, const int* in_sizes, int n_in,
                              void* d_out, int out_size, void* d_ws, size_t ws_size,
                              hipStream_t stream)
{
    const float* x       = (const float*)d_in[0];
    const float* labels  = (const float*)d_in[1];
    const float* centers = (const float*)d_in[2];
    float* out      = (float*)d_out;
    float* partials = (float*)d_ws;   // 8192 floats, every slot overwritten

    center_loss_kernel<<<BATCH, 256, 0, stream>>>(x, labels, centers, partials);
    reduce_kernel<<<1, 256, 0, stream>>>(partials, out);
}